// Round 4
// baseline (514.396 us; speedup 1.0000x reference)
//
#include <hip/hip_runtime.h>

// B=1e6 rows x 100 f32. Per row, t=0..19:
//   q = row[4t..4t+3]; irel_t = row[80+t]
//   (c,b,_) = softmax3(q.xyz); rho = sigmoid(q.w)
//   wf = max(1.02 - c - b + rho*irel, 1e-6)
//   acc += sqrt(min(c*x,1e6))*CU_K[t] + sqrt(min(x*(1+b*INVPD[t]),1e6))*LU_K[t]
//   x = x*wf + 1
// final: acc += sqrt(min(x,1e6))*FIN_K
//
// Round-4 structure: two tiles per block, double-buffered LDS, counted
// s_waitcnt vmcnt(25) so tile-B's 25 global_load_lds stay in flight across
// tile-A's compute (single-wave blocks -> no s_barrier needed at all).
// Bytes identical; tests whether the kernel was latency-gapped or BW-bound.

#define T_STEPS 20
#define BLOCK 64
#define F4_PER_ROW 25               // 100 floats = 25 float4; odd -> conflict-free b128
#define TILE_F4 (BLOCK * F4_PER_ROW)  // 1600 float4 = 25.6 KB

struct Consts {
    float cu_k[T_STEPS];   // f32(pbar_t) * 0.005  (2 * 1/400 folded)
    float lu_k[T_STEPS];   // f32(pd_t * D_t) * 0.005
    float invpd[T_STEPS];  // 1 / (f32(pd_t) + 1e-6)
    float fin_k;           // f32(pbar_20) * 0.005
};

// Compile-time reproduction of the numpy double-precision schedule:
// D_t = 0.995^t, pd_t = linspace(0.001,0.01,21), Pbar = (1-cumsum(pd))*D.
constexpr Consts make_consts() {
    Consts c{};
    double cum = 0.0;
    for (int t = 0; t <= T_STEPS; ++t) {
        double Dt = 1.0;
        for (int k = 0; k < t; ++k) Dt *= 0.995;
        const double pd = 0.001 + (double)t * (0.009 / 20.0);
        cum += pd;
        const double pbar = (1.0 - cum) * Dt;
        if (t < T_STEPS) {
            c.cu_k[t]  = (float)pbar * 0.005f;
            c.lu_k[t]  = (float)(pd * Dt) * 0.005f;
            c.invpd[t] = 1.0f / ((float)pd + 1e-6f);
        } else {
            c.fin_k = (float)pbar * 0.005f;
        }
    }
    return c;
}

constexpr Consts CST = make_consts();

__device__ __forceinline__ float compute_row(const float4* __restrict__ rowp) {
    constexpr float L2E = 1.4426950408889634f;   // log2(e)
    float x = 1.0f;
    float acc = 0.0f;

    #pragma unroll
    for (int g5 = 0; g5 < 5; ++g5) {
        const float4 irq = rowp[20 + g5];          // irel[4g5 .. 4g5+3]
        const float ir0[4] = {irq.x, irq.y, irq.z, irq.w};
        #pragma unroll
        for (int j = 0; j < 4; ++j) {
            const int t = g5 * 4 + j;
            const float4 q = rowp[t];              // c_raw,b_raw,i_raw,rho_raw

            // softmax3 without max-subtraction (inputs bounded ~[-6,6])
            const float ec = __builtin_amdgcn_exp2f(q.x * L2E);
            const float eb = __builtin_amdgcn_exp2f(q.y * L2E);
            const float ei = __builtin_amdgcn_exp2f(q.z * L2E);
            const float inv = __builtin_amdgcn_rcpf(ec + eb + ei);
            const float c = ec * inv;
            const float b = eb * inv;

            // sigmoid
            const float rho =
                __builtin_amdgcn_rcpf(1.0f + __builtin_amdgcn_exp2f(-q.w * L2E));

            float wf = fmaf(rho, ir0[j], (1.02f - c) - b);
            wf = fmaxf(wf, 1e-6f);

            // utilities use x BEFORE the scan update
            const float cx = fminf(c * x, 1e6f);
            acc = fmaf(__builtin_amdgcn_sqrtf(cx), CST.cu_k[t], acc);

            const float lt = fminf(fmaf(b, CST.invpd[t], 1.0f) * x, 1e6f);
            acc = fmaf(__builtin_amdgcn_sqrtf(lt), CST.lu_k[t], acc);

            x = fmaf(x, wf, 1.0f);                 // scan step
        }
    }

    // terminal bequest on x[T]
    acc = fmaf(__builtin_amdgcn_sqrtf(fminf(x, 1e6f)), CST.fin_k, acc);
    return acc;
}

__global__ __launch_bounds__(BLOCK)
void life_utility_kernel(const float4* __restrict__ in, float* __restrict__ out,
                         int B) {
    __shared__ float4 bufA[TILE_F4];   // 25.6 KB
    __shared__ float4 bufB[TILE_F4];   // 25.6 KB  (51.2 KB total -> 3 blocks/CU)

    const int tid = threadIdx.x;
    const int nTiles = B / BLOCK;                 // 15625 (B % 64 == 0)
    const int tile0 = blockIdx.x * 2;
    const int tile1 = tile0 + 1;
    const bool has2 = (tile1 < nTiles);           // last block (odd count) has 1 tile

    // Stage tile A: 25 coalesced global_load_lds x 16B (1KB/instr), linear
    // k-major layout = exactly the wave-uniform-base + lane*16 write pattern.
    const long long baseA = (long long)tile0 * TILE_F4;
    #pragma unroll
    for (int k = 0; k < F4_PER_ROW; ++k) {
        const int idx = k * BLOCK + tid;
        __builtin_amdgcn_global_load_lds(
            (const __attribute__((address_space(1))) void*)(in + baseA + idx),
            (__attribute__((address_space(3))) void*)(&bufA[idx]), 16, 0, 0);
    }

    if (has2) {
        // Stage tile B immediately; its 25 loads remain in flight across
        // tile A's compute (counted vmcnt below, never a full drain here).
        const long long baseB = (long long)tile1 * TILE_F4;
        #pragma unroll
        for (int k = 0; k < F4_PER_ROW; ++k) {
            const int idx = k * BLOCK + tid;
            __builtin_amdgcn_global_load_lds(
                (const __attribute__((address_space(1))) void*)(in + baseB + idx),
                (__attribute__((address_space(3))) void*)(&bufB[idx]), 16, 0, 0);
        }
        // Wait for the 25 oldest (tile A) only; 25 (tile B) still outstanding.
        asm volatile("s_waitcnt vmcnt(25)" ::: "memory");
    } else {
        asm volatile("s_waitcnt vmcnt(0)" ::: "memory");
    }
    __builtin_amdgcn_sched_barrier(0);   // fence: no LDS reads hoisted above wait

    // Single-wave block: vmcnt is a wave-level counter and global_load_lds
    // retires in issue order (m135), so no s_barrier is needed anywhere.
    out[tile0 * BLOCK + tid] = compute_row(&bufA[tid * F4_PER_ROW]);

    if (has2) {
        asm volatile("s_waitcnt vmcnt(0)" ::: "memory");  // drain tile B (+storeA, harmless)
        __builtin_amdgcn_sched_barrier(0);
        out[tile1 * BLOCK + tid] = compute_row(&bufB[tid * F4_PER_ROW]);
    }
}

extern "C" void kernel_launch(void* const* d_in, const int* in_sizes, int n_in,
                              void* d_out, int out_size, void* d_ws, size_t ws_size,
                              hipStream_t stream) {
    const float4* in = (const float4*)d_in[0];
    float* out = (float*)d_out;
    const int B = in_sizes[0] / (5 * T_STEPS);   // 1,000,000

    const int nTiles = B / BLOCK;                // 15625
    const int nblk = (nTiles + 1) / 2;           // 7813 blocks x 2 tiles
    life_utility_kernel<<<nblk, BLOCK, 0, stream>>>(in, out, B);
}